// Round 3
// baseline (215.801 us; speedup 1.0000x reference)
//
#include <hip/hip_runtime.h>
#include <math.h>

#define B_G   256
#define IN_D  128
#define FD    256
#define HID   256
#define OUT_D 128
#define TXT   512
#define XKS   136   // X LDS k-stride (ushorts): 272 B/row; A-frag b128 reads spread
                    // 8 lanes/bank-group (even) -> no swizzle needed at this stride

typedef short bf16x8 __attribute__((ext_vector_type(8)));
typedef float f32x4  __attribute__((ext_vector_type(4)));

// ---------------------------------------------------------------------------
// bf16 split helpers (RNE)
// ---------------------------------------------------------------------------
__device__ __forceinline__ unsigned bf_rne(float x) {
    unsigned u = __float_as_uint(x);
    u += 0x7fffu + ((u >> 16) & 1u);
    return u >> 16;
}
__device__ __forceinline__ float bf_to_f(unsigned h) {
    return __uint_as_float(h << 16);
}
__device__ __forceinline__ void split2(float a0, float a1, unsigned& hp, unsigned& lp) {
    unsigned h0 = bf_rne(a0), h1 = bf_rne(a1);
    float r0 = a0 - bf_to_f(h0), r1 = a1 - bf_to_f(h1);
    hp = h0 | (h1 << 16);
    lp = bf_rne(r0) | (bf_rne(r1) << 16);
}

// ---------------------------------------------------------------------------
// Kernel A (grid 261): fused prep.  (unchanged)
// ---------------------------------------------------------------------------
__global__ __launch_bounds__(256) void k_prepA(
    const float* __restrict__ text_emb, const float* __restrict__ Wq,
    const float* __restrict__ bq, const float* __restrict__ Wk,
    const float* __restrict__ W0, const int* __restrict__ lens,
    float* __restrict__ qk, int* __restrict__ offsets, float* __restrict__ hsum,
    unsigned short* __restrict__ W0sH, unsigned short* __restrict__ W0sL)
{
    int blk = blockIdx.x, t = threadIdx.x;
    __shared__ float te[TXT];
    __shared__ float q[FD];
    __shared__ int   sc[B_G];

    if (blk < 256) {
        int b = blk;
        hsum[b * FD + t] = 0.f;
        for (int i = t; i < TXT; i += 256) te[i] = text_emb[(size_t)b * TXT + i];
        __syncthreads();
        float acc = bq[t];
        for (int k = 0; k < TXT; k++) acc = fmaf(te[k], Wq[k * FD + t], acc);
        q[t] = acc;
        __syncthreads();
        float a2 = 0.f;
        for (int f = 0; f < FD; f++) a2 = fmaf(Wk[t * FD + f], q[f], a2);
        qk[b * FD + t] = a2;
    } else if (blk < 260) {
        int e = (blk - 256) * 256 + t;   // 0..1023
        int kc = e >> 8, c = e & 255;
        size_t base = (size_t)(kc * 256 + c) * 32;
        for (int kk = 0; kk < 32; kk++) {
            float v = W0[(size_t)(kc * 32 + kk) * FD + c];
            unsigned h = bf_rne(v);
            float r = v - bf_to_f(h);
            W0sH[base + kk] = (unsigned short)h;
            W0sL[base + kk] = (unsigned short)bf_rne(r);
        }
    } else {
        // parallel inclusive scan of lens (256 elements, 8 steps)
        sc[t] = lens[t];
        __syncthreads();
        for (int d = 1; d < 256; d <<= 1) {
            int v = (t >= d) ? sc[t - d] : 0;
            __syncthreads();
            sc[t] += v;
            __syncthreads();
        }
        offsets[t + 1] = sc[t];
        if (t == 0) offsets[0] = 0;
    }
}

// ---------------------------------------------------------------------------
// K1: bf16x3 MFMA.  v3: 4 blocks/CU (VGPR-dieted: chunked staging, B-frags
// loaded per-j so live B regs are 8 not 32).  acc 64 + A 32 + B 8 + misc
// ~= 124 VGPR target for __launch_bounds__(256,4).  LDS 37.9 KB x4 <= 160 KB.
// ---------------------------------------------------------------------------
__global__ __launch_bounds__(256, 4) void k_l0_mfma(
    const float* __restrict__ X,
    const unsigned short* __restrict__ W0sH, const unsigned short* __restrict__ W0sL,
    const float* __restrict__ b0, const float* __restrict__ qk,
    const int* __restrict__ offsets,
    float* __restrict__ scores, float* __restrict__ hsum)
{
    int b = blockIdx.y;
    int off = offsets[b], len = offsets[b + 1] - off;
    int n0 = blockIdx.x * 64;
    if (n0 >= len) return;
    int nvalid = min(64, len - n0);

    __shared__ __align__(16) unsigned short XsH[64 * XKS], XsL[64 * XKS]; // 2x17408 B
    __shared__ float qks[FD];
    __shared__ float bsh[FD];
    __shared__ float red[4][64];

    int tid = threadIdx.x;
    int lane = tid & 63, w = tid >> 6;
    int ln = lane & 15, quad = lane >> 4;

    qks[tid] = qk[b * FD + tid];
    bsh[tid] = b0[tid];

    // ---- stage X (full K): thread -> node tid>>2, k-range (tid&3)*32..+32.
    //      8-float chunks keep peak live regs ~10 instead of 32. ----
    {
        int node_s = tid >> 2, ks = (tid & 3) * 32;
        const float4* Xr4 = (const float4*)(X + (size_t)(off + n0 + node_s) * IN_D + ks);
        bool v = (node_s < nvalid);
#pragma unroll
        for (int g = 0; g < 4; g++) {
            float4 a, c4;
            if (v) { a = Xr4[2 * g]; c4 = Xr4[2 * g + 1]; }
            else   { a = make_float4(0.f, 0.f, 0.f, 0.f); c4 = a; }
            uint4 hq, lq;
            split2(a.x,  a.y,  hq.x, lq.x);
            split2(a.z,  a.w,  hq.y, lq.y);
            split2(c4.x, c4.y, hq.z, lq.z);
            split2(c4.z, c4.w, hq.w, lq.w);
            *(uint4*)&XsH[node_s * XKS + ks + g * 8] = hq;
            *(uint4*)&XsL[node_s * XKS + ks + g * 8] = lq;
        }
    }
    __syncthreads();

    f32x4 acc[4][4] = {};
#pragma unroll
    for (int kc = 0; kc < 4; kc++) {
        bf16x8 AH[4], AL[4];
#pragma unroll
        for (int i = 0; i < 4; i++) {
            AH[i] = *(const bf16x8*)&XsH[(16 * i + ln) * XKS + kc * 32 + quad * 8];
            AL[i] = *(const bf16x8*)&XsL[(16 * i + ln) * XKS + kc * 32 + quad * 8];
        }
#pragma unroll
        for (int j = 0; j < 4; j++) {
            int c = 64 * w + 16 * j + ln;
            size_t base = (size_t)(kc * 256 + c) * 32 + quad * 8;
            bf16x8 BH = *(const bf16x8*)&W0sH[base];
            bf16x8 BL = *(const bf16x8*)&W0sL[base];
#pragma unroll
            for (int i = 0; i < 4; i++) {
                acc[i][j] = __builtin_amdgcn_mfma_f32_16x16x32_bf16(AH[i], BH, acc[i][j], 0, 0, 0);
                acc[i][j] = __builtin_amdgcn_mfma_f32_16x16x32_bf16(AH[i], BL, acc[i][j], 0, 0, 0);
                acc[i][j] = __builtin_amdgcn_mfma_f32_16x16x32_bf16(AL[i], BH, acc[i][j], 0, 0, 0);
            }
        }
    }

    // ---- epilogue: bias+relu+mask -> score partials & column sums ----
    float sp[4][4];
    float cs[4] = {0.f, 0.f, 0.f, 0.f};
#pragma unroll
    for (int i = 0; i < 4; i++)
#pragma unroll
        for (int r = 0; r < 4; r++) sp[i][r] = 0.f;

#pragma unroll
    for (int i = 0; i < 4; i++)
#pragma unroll
        for (int j = 0; j < 4; j++) {
            int c = 64 * w + 16 * j + ln;
            float bb = bsh[c], qv = qks[c];
#pragma unroll
            for (int r = 0; r < 4; r++) {
                int node = 16 * i + 4 * quad + r;
                float h = acc[i][j][r] + bb;
                h = (h > 0.f && node < nvalid) ? h : 0.f;
                sp[i][r] = fmaf(h, qv, sp[i][r]);
                cs[j] += h;
            }
        }
    // reduce score partials over ln (16 cols) in-wave
#pragma unroll
    for (int i = 0; i < 4; i++)
#pragma unroll
        for (int r = 0; r < 4; r++) {
            float s = sp[i][r];
            s += __shfl_xor(s, 1); s += __shfl_xor(s, 2);
            s += __shfl_xor(s, 4); s += __shfl_xor(s, 8);
            sp[i][r] = s;
        }
    if (ln == 0) {
#pragma unroll
        for (int i = 0; i < 4; i++)
#pragma unroll
            for (int r = 0; r < 4; r++)
                red[w][16 * i + 4 * quad + r] = sp[i][r];
    }
    // hsum: reduce over quads (nodes), one atomic per col
#pragma unroll
    for (int j = 0; j < 4; j++) {
        float s = cs[j];
        s += __shfl_xor(s, 16); s += __shfl_xor(s, 32);
        if (quad == 0) atomicAdd(&hsum[b * FD + 64 * w + 16 * j + ln], s);
    }
    __syncthreads();
    if (tid < 64 && tid < nvalid)
        scores[off + n0 + tid] = red[0][tid] + red[1][tid] + red[2][tid] + red[3][tid];
}

// ---------------------------------------------------------------------------
// K2+K3 fused: per-graph softmax stats + wvec GEMV + piecewise-linear walk.
// One 1024-thread block per graph.  Saves a launch, the wvec/smax/dinv
// global round-trip, and a redundant scores pass (exp kept in registers).
// ---------------------------------------------------------------------------
__global__ __launch_bounds__(1024) void k_graph_walk(
    const float* __restrict__ scores, const float* __restrict__ hsum,
    const float* __restrict__ Wv, const float* __restrict__ bv,
    const float* __restrict__ Wo, const float* __restrict__ bo,
    const float* __restrict__ W2, const float* __restrict__ b2,
    const int* __restrict__ offsets, float* __restrict__ Y)
{
    int b = blockIdx.x, tid = threadIdx.x;
    int off = offsets[b], len = offsets[b + 1] - off;
    int t = tid & 255, g = tid >> 8;

    __shared__ float redm[16], reds[16];
    __shared__ float hs[FD], vs[FD];
    __shared__ float part[4][FD];
    __shared__ float wv2[HID], boS[HID], b2s[OUT_D];
    __shared__ float tOrig[256];
    __shared__ float tS[256], dwS[256], dbS[256];
    __shared__ int   kS[256];
    __shared__ int   cnt[257], startS[257];
    __shared__ float A0s[OUT_D], C0s[OUT_D];
    __shared__ float segA[8][OUT_D], segC[8][OUT_D];
    __shared__ __align__(16) char ops_raw[656 * 16];
    float* opA = (float*)ops_raw;                // [656]
    float* opB = (float*)(ops_raw + 2624);       // [656]
    int*   opN = (int*)(ops_raw + 5248);         // [656]
    int*   opK = (int*)(ops_raw + 7872);         // [656]

    // ---- prologue loads (consumed only after barriers below) ----
    if (g == 0) { boS[t] = bo[t]; hs[t] = hsum[b * FD + t]; }
    if (tid < OUT_D) b2s[tid] = b2[tid];
    if (tid <= 256) cnt[tid] = 0;
    float s_n = (tid < len) ? scores[off + tid] : -INFINITY;

    // ---- G1: max over scores ----
    float m = s_n;
#pragma unroll
    for (int d = 1; d < 64; d <<= 1) m = fmaxf(m, __shfl_xor(m, d));
    if ((tid & 63) == 0) redm[tid >> 6] = m;
    __syncthreads();
    m = -INFINITY;
#pragma unroll
    for (int k = 0; k < 16; k++) m = fmaxf(m, redm[k]);

    // ---- G2: exp + sum ----
    float e_n = (tid < len) ? expf(s_n - m) : 0.f;
    float s = e_n;
#pragma unroll
    for (int d = 1; d < 64; d <<= 1) s += __shfl_xor(s, d);
    if ((tid & 63) == 0) reds[tid >> 6] = s;
    __syncthreads();
    s = 0.f;
#pragma unroll
    for (int k = 0; k < 16; k++) s += reds[k];
    float dinv = 1.0f / s;

    // ---- G3: wvec = (hsum @ Wv + len*bv) @ Wo  (4-way split reduction) ----
    float acc = (g == 0) ? (float)len * bv[t] : 0.f;
    for (int f = 64 * g; f < 64 * g + 64; f++) acc = fmaf(hs[f], Wv[f * FD + t], acc);
    part[g][t] = acc;
    __syncthreads();
    if (g == 0) vs[t] = part[0][t] + part[1][t] + part[2][t] + part[3][t];
    __syncthreads();
    float a2 = 0.f;
    for (int f = 64 * g; f < 64 * g + 64; f++) a2 = fmaf(vs[f], Wo[f * HID + t], a2);
    part[g][t] = a2;
    __syncthreads();
    if (g == 0) wv2[t] = part[0][t] + part[1][t] + part[2][t] + part[3][t];
    __syncthreads();   // wv2 ready

    // ---- P0: event construction (active(k,p) := w*p+bo > 0 flips at t=-bo/w) ----
    bool real = false;
    if (tid < 256) {
        float wv = wv2[tid], bvv = boS[tid];
        bool isev = (wv > 0.f && bvv < 0.f) || (wv < 0.f && bvv > 0.f);
        float tk = isev ? (-bvv / wv) : INFINITY;
        real = isev && (tk < INFINITY);
        tOrig[tid] = real ? tk : INFINITY;
    }
    __syncthreads();

    // ---- P1: rank-compare sort of events; A0/C0 partials in parallel ----
    if (tid < 256) {
        float tk = tOrig[tid];
        int r = 0;
        for (int j = 0; j < 256; j++) {
            float tj = tOrig[j];
            r += (tj < tk || (tj == tk && j < tid)) ? 1 : 0;
        }
        tS[r] = tk;
        kS[r] = tid;
        float wv = wv2[tid], bvv = boS[tid];
        dwS[r] = real ? fabsf(wv) : 0.f;   // add-event (w>0): +w ; remove-event (w<0): -w
        dbS[r] = real ? -fabsf(bvv) : 0.f; // add-event: +bo (bo<0) ; remove-event: -bo (bo>0)
    }
    // A0/C0: active set at p->0+ is {k: bo>0 or (bo==0 && w>0)}
    {
        int q = tid >> 7, c = tid & 127;
        float pa = 0.f, pc = 0.f;
        for (int k = q * 32; k < q * 32 + 32; ++k) {
            float v = W2[(size_t)k * OUT_D + c];
            float wv = wv2[k], bvv = boS[k];
            bool ini = (bvv > 0.f) || (bvv == 0.f && wv > 0.f);
            pa = fmaf(ini ? wv : 0.f, v, pa);
            pc = fmaf(ini ? bvv : 0.f, v, pc);
        }
        segA[q][c] = pa; segC[q][c] = pc;
    }
    int nE = __syncthreads_count(real);

    // ---- P2: per-node p + rank (binary search) + histogram; A0/C0 reduce ----
    float p_n = 0.f; int r_n = 0;
    if (tid < len) {
        p_n = e_n * dinv;
        int r = 0;
#pragma unroll
        for (int st = 128; st > 0; st >>= 1)
            if (tS[r + st - 1] < p_n) r += st;
        r_n = r;
        atomicAdd(&cnt[r], 1);
    }
    if (tid < OUT_D) {
        float sa = 0.f, sc2 = 0.f;
#pragma unroll
        for (int q = 0; q < 8; q++) { sa += segA[q][tid]; sc2 += segC[q][tid]; }
        A0s[tid] = sa; C0s[tid] = sc2;
    }
    __syncthreads();

    // ---- P3: exclusive scan of cnt[0..255] by wave 0 (shfl, no barriers) ----
    if (tid < 64) {
        int l = tid;
        int v0 = cnt[4 * l], v1 = cnt[4 * l + 1], v2 = cnt[4 * l + 2], v3 = cnt[4 * l + 3];
        int s0 = v0, s1 = s0 + v1, s2 = s1 + v2, s3 = s2 + v3;
        int run = s3;
#pragma unroll
        for (int d = 1; d < 64; d <<= 1) {
            int t2 = __shfl_up(run, d);
            if (l >= d) run += t2;
        }
        int base = run - s3;   // exclusive over lanes
        startS[4 * l + 0] = base;      cnt[4 * l + 0] = base;
        startS[4 * l + 1] = base + s0; cnt[4 * l + 1] = base + s0;
        startS[4 * l + 2] = base + s1; cnt[4 * l + 2] = base + s1;
        startS[4 * l + 3] = base + s2; cnt[4 * l + 3] = base + s2;
        if (l == 63) { startS[256] = base + s3; cnt[256] = base + s3; }
    }
    __syncthreads();

    int L    = len + nE;
    int Lpad = (L + 7) & ~7;
    int Lseg = ((Lpad + 63) >> 6) << 3;   // ceil(Lpad/8) rounded to mult of 8; <=80

    // ---- P4: build merged op list (node scatter + events + zero padding) ----
    if (tid < len) {
        int slot = atomicAdd(&cnt[r_n], 1);
        int pos = slot + r_n;
        opA[pos] = p_n; opB[pos] = 0.f; opN[pos] = tid; opK[pos] = 0;
    }
    if (tid < nE) {
        int pos = startS[tid + 1] + tid;
        opA[pos] = dwS[tid]; opB[pos] = dbS[tid]; opN[pos] = -1; opK[pos] = kS[tid];
    }
    for (int i = L + tid; i < 648; i += 1024) {
        opA[i] = 0.f; opB[i] = 0.f; opN[i] = -1; opK[i] = 0;
    }
    __syncthreads();

    // ---- P5: per-segment event-delta sums (contiguous j-range per segment) ----
    int sg = tid >> 7, c = tid & 127;
    {
        int iBeg = sg * Lseg, iEnd = iBeg + Lseg;
        int lo = 0, hi = nE;
        while (lo < hi) {
            int mid = (lo + hi) >> 1;
            if (startS[mid + 1] + mid < iBeg) lo = mid + 1; else hi = mid;
        }
        float dA = 0.f, dC = 0.f;
        for (int j = lo; j < nE && (startS[j + 1] + j) < iEnd; ++j) {
            float v = W2[(size_t)kS[j] * OUT_D + c];
            dA = fmaf(dwS[j], v, dA);
            dC = fmaf(dbS[j], v, dC);
        }
        segA[sg][c] = dA; segC[sg][c] = dC;
    }
    __syncthreads();

    // ---- P6: 8x128 concurrent segment walks; ring prefetch 8 deep.
    //          W2 row prefetch only when the future op is an event
    //          (wave-uniform branch: op index uniform across the wave). ----
    {
        float A = A0s[c], C = C0s[c];
        for (int s2 = 0; s2 < sg; ++s2) { A += segA[s2][c]; C += segC[s2][c]; }
        float b2v = b2s[c];
        float* Yb = Y + (size_t)off * OUT_D + c;
        int i0 = sg * Lseg;

        float rA[8], rB[8], rV[8] = {0,0,0,0,0,0,0,0};
        int rN[8], rK[8];
#pragma unroll
        for (int u = 0; u < 8; ++u) {
            rA[u] = opA[i0 + u]; rB[u] = opB[i0 + u];
            rN[u] = opN[i0 + u]; rK[u] = opK[i0 + u];
        }
#pragma unroll
        for (int u = 0; u < 8; ++u)
            if (rN[u] < 0) rV[u] = W2[(size_t)rK[u] * OUT_D + c];

        for (int i0w = i0; i0w < i0 + Lseg; i0w += 8) {
#pragma unroll
            for (int u = 0; u < 8; ++u) {
                int i = i0w + u;
                float aI = rA[u], bI = rB[u], vv = rV[u];
                int nI = rN[u];
                rA[u] = opA[i + 8]; rB[u] = opB[i + 8];
                rN[u] = opN[i + 8]; rK[u] = opK[i + 8];
                if (rN[u] < 0) rV[u] = W2[(size_t)rK[u] * OUT_D + c];
                if (nI >= 0) Yb[(size_t)nI * OUT_D] = fmaf(aI, A, C) + b2v;
                else { A = fmaf(aI, vv, A); C = fmaf(bI, vv, C); }
            }
        }
    }
}

// ---------------------------------------------------------------------------
extern "C" void kernel_launch(void* const* d_in, const int* in_sizes, int n_in,
                              void* d_out, int out_size, void* d_ws, size_t ws_size,
                              hipStream_t stream)
{
    const float* X        = (const float*)d_in[0];
    const float* text_emb = (const float*)d_in[1];
    const int*   lens     = (const int*)d_in[2];
    const float* W0       = (const float*)d_in[3];
    const float* b0       = (const float*)d_in[4];
    const float* Wq       = (const float*)d_in[5];
    const float* bq       = (const float*)d_in[6];
    const float* Wk       = (const float*)d_in[7];
    // d_in[8] = bk : softmax-invariant, unused
    const float* Wv       = (const float*)d_in[9];
    const float* bv       = (const float*)d_in[10];
    const float* Wo       = (const float*)d_in[11];
    const float* bo       = (const float*)d_in[12];
    const float* W2       = (const float*)d_in[13];
    const float* b2       = (const float*)d_in[14];
    float* Y = (float*)d_out;

    char* base = (char*)d_ws;
    size_t o = 0;
    int*   offsets = (int*)(base + o);            o += 1088;
    float* qkbuf   = (float*)(base + o);          o += 262144;
    float* hsum    = (float*)(base + o);          o += 262144;
    float* scores  = (float*)(base + o);          o += 262144;
    unsigned short* W0sH = (unsigned short*)(base + o); o += 65536;
    unsigned short* W0sL = (unsigned short*)(base + o); o += 65536;

    k_prepA<<<261, 256, 0, stream>>>(text_emb, Wq, bq, Wk, W0, lens,
                                     qkbuf, offsets, hsum, W0sH, W0sL);
    k_l0_mfma<<<dim3(6, B_G), 256, 0, stream>>>(X, W0sH, W0sL, b0, qkbuf, offsets, scores, hsum);
    k_graph_walk<<<B_G, 1024, 0, stream>>>(scores, hsum, Wv, bv, Wo, bo, W2, b2, offsets, Y);
}

// Round 4
// 204.984 us; speedup vs baseline: 1.0528x; 1.0528x over previous
//
#include <hip/hip_runtime.h>
#include <math.h>

#define B_G   256
#define IN_D  128
#define FD    256
#define HID   256
#define OUT_D 128
#define TXT   512
#define XKS   136   // X LDS k-stride (ushorts): 272 B/row; A-frag b128 reads spread
                    // 8 lanes/bank-group (even) -> no swizzle needed at this stride

typedef short bf16x8 __attribute__((ext_vector_type(8)));
typedef float f32x4  __attribute__((ext_vector_type(4)));

// ---------------------------------------------------------------------------
// bf16 split helpers (RNE)
// ---------------------------------------------------------------------------
__device__ __forceinline__ unsigned bf_rne(float x) {
    unsigned u = __float_as_uint(x);
    u += 0x7fffu + ((u >> 16) & 1u);
    return u >> 16;
}
__device__ __forceinline__ float bf_to_f(unsigned h) {
    return __uint_as_float(h << 16);
}
__device__ __forceinline__ void split2(float a0, float a1, unsigned& hp, unsigned& lp) {
    unsigned h0 = bf_rne(a0), h1 = bf_rne(a1);
    float r0 = a0 - bf_to_f(h0), r1 = a1 - bf_to_f(h1);
    hp = h0 | (h1 << 16);
    lp = bf_rne(r0) | (bf_rne(r1) << 16);
}

// ---------------------------------------------------------------------------
// Kernel A (grid 261): fused prep.  (unchanged)
// ---------------------------------------------------------------------------
__global__ __launch_bounds__(256) void k_prepA(
    const float* __restrict__ text_emb, const float* __restrict__ Wq,
    const float* __restrict__ bq, const float* __restrict__ Wk,
    const float* __restrict__ W0, const int* __restrict__ lens,
    float* __restrict__ qk, int* __restrict__ offsets, float* __restrict__ hsum,
    unsigned short* __restrict__ W0sH, unsigned short* __restrict__ W0sL)
{
    int blk = blockIdx.x, t = threadIdx.x;
    __shared__ float te[TXT];
    __shared__ float q[FD];
    __shared__ int   sc[B_G];

    if (blk < 256) {
        int b = blk;
        hsum[b * FD + t] = 0.f;
        for (int i = t; i < TXT; i += 256) te[i] = text_emb[(size_t)b * TXT + i];
        __syncthreads();
        float acc = bq[t];
        for (int k = 0; k < TXT; k++) acc = fmaf(te[k], Wq[k * FD + t], acc);
        q[t] = acc;
        __syncthreads();
        float a2 = 0.f;
        for (int f = 0; f < FD; f++) a2 = fmaf(Wk[t * FD + f], q[f], a2);
        qk[b * FD + t] = a2;
    } else if (blk < 260) {
        int e = (blk - 256) * 256 + t;   // 0..1023
        int kc = e >> 8, c = e & 255;
        size_t base = (size_t)(kc * 256 + c) * 32;
        for (int kk = 0; kk < 32; kk++) {
            float v = W0[(size_t)(kc * 32 + kk) * FD + c];
            unsigned h = bf_rne(v);
            float r = v - bf_to_f(h);
            W0sH[base + kk] = (unsigned short)h;
            W0sL[base + kk] = (unsigned short)bf_rne(r);
        }
    } else {
        // parallel inclusive scan of lens (256 elements, 8 steps)
        sc[t] = lens[t];
        __syncthreads();
        for (int d = 1; d < 256; d <<= 1) {
            int v = (t >= d) ? sc[t - d] : 0;
            __syncthreads();
            sc[t] += v;
            __syncthreads();
        }
        offsets[t + 1] = sc[t];
        if (t == 0) offsets[0] = 0;
    }
}

// ---------------------------------------------------------------------------
// K1: bf16x3 MFMA.  (unchanged from round 3)
// ---------------------------------------------------------------------------
__global__ __launch_bounds__(256, 4) void k_l0_mfma(
    const float* __restrict__ X,
    const unsigned short* __restrict__ W0sH, const unsigned short* __restrict__ W0sL,
    const float* __restrict__ b0, const float* __restrict__ qk,
    const int* __restrict__ offsets,
    float* __restrict__ scores, float* __restrict__ hsum)
{
    int b = blockIdx.y;
    int off = offsets[b], len = offsets[b + 1] - off;
    int n0 = blockIdx.x * 64;
    if (n0 >= len) return;
    int nvalid = min(64, len - n0);

    __shared__ __align__(16) unsigned short XsH[64 * XKS], XsL[64 * XKS]; // 2x17408 B
    __shared__ float qks[FD];
    __shared__ float bsh[FD];
    __shared__ float red[4][64];

    int tid = threadIdx.x;
    int lane = tid & 63, w = tid >> 6;
    int ln = lane & 15, quad = lane >> 4;

    qks[tid] = qk[b * FD + tid];
    bsh[tid] = b0[tid];

    // ---- stage X (full K): thread -> node tid>>2, k-range (tid&3)*32..+32 ----
    {
        int node_s = tid >> 2, ks = (tid & 3) * 32;
        const float4* Xr4 = (const float4*)(X + (size_t)(off + n0 + node_s) * IN_D + ks);
        bool v = (node_s < nvalid);
#pragma unroll
        for (int g = 0; g < 4; g++) {
            float4 a, c4;
            if (v) { a = Xr4[2 * g]; c4 = Xr4[2 * g + 1]; }
            else   { a = make_float4(0.f, 0.f, 0.f, 0.f); c4 = a; }
            uint4 hq, lq;
            split2(a.x,  a.y,  hq.x, lq.x);
            split2(a.z,  a.w,  hq.y, lq.y);
            split2(c4.x, c4.y, hq.z, lq.z);
            split2(c4.z, c4.w, hq.w, lq.w);
            *(uint4*)&XsH[node_s * XKS + ks + g * 8] = hq;
            *(uint4*)&XsL[node_s * XKS + ks + g * 8] = lq;
        }
    }
    __syncthreads();

    f32x4 acc[4][4] = {};
#pragma unroll
    for (int kc = 0; kc < 4; kc++) {
        bf16x8 AH[4], AL[4];
#pragma unroll
        for (int i = 0; i < 4; i++) {
            AH[i] = *(const bf16x8*)&XsH[(16 * i + ln) * XKS + kc * 32 + quad * 8];
            AL[i] = *(const bf16x8*)&XsL[(16 * i + ln) * XKS + kc * 32 + quad * 8];
        }
#pragma unroll
        for (int j = 0; j < 4; j++) {
            int c = 64 * w + 16 * j + ln;
            size_t base = (size_t)(kc * 256 + c) * 32 + quad * 8;
            bf16x8 BH = *(const bf16x8*)&W0sH[base];
            bf16x8 BL = *(const bf16x8*)&W0sL[base];
#pragma unroll
            for (int i = 0; i < 4; i++) {
                acc[i][j] = __builtin_amdgcn_mfma_f32_16x16x32_bf16(AH[i], BH, acc[i][j], 0, 0, 0);
                acc[i][j] = __builtin_amdgcn_mfma_f32_16x16x32_bf16(AH[i], BL, acc[i][j], 0, 0, 0);
                acc[i][j] = __builtin_amdgcn_mfma_f32_16x16x32_bf16(AL[i], BH, acc[i][j], 0, 0, 0);
            }
        }
    }

    // ---- epilogue: bias+relu+mask -> score partials & column sums ----
    float sp[4][4];
    float cs[4] = {0.f, 0.f, 0.f, 0.f};
#pragma unroll
    for (int i = 0; i < 4; i++)
#pragma unroll
        for (int r = 0; r < 4; r++) sp[i][r] = 0.f;

#pragma unroll
    for (int i = 0; i < 4; i++)
#pragma unroll
        for (int j = 0; j < 4; j++) {
            int c = 64 * w + 16 * j + ln;
            float bb = bsh[c], qv = qks[c];
#pragma unroll
            for (int r = 0; r < 4; r++) {
                int node = 16 * i + 4 * quad + r;
                float h = acc[i][j][r] + bb;
                h = (h > 0.f && node < nvalid) ? h : 0.f;
                sp[i][r] = fmaf(h, qv, sp[i][r]);
                cs[j] += h;
            }
        }
    // reduce score partials over ln (16 cols) in-wave
#pragma unroll
    for (int i = 0; i < 4; i++)
#pragma unroll
        for (int r = 0; r < 4; r++) {
            float s = sp[i][r];
            s += __shfl_xor(s, 1); s += __shfl_xor(s, 2);
            s += __shfl_xor(s, 4); s += __shfl_xor(s, 8);
            sp[i][r] = s;
        }
    if (ln == 0) {
#pragma unroll
        for (int i = 0; i < 4; i++)
#pragma unroll
            for (int r = 0; r < 4; r++)
                red[w][16 * i + 4 * quad + r] = sp[i][r];
    }
    // hsum: reduce over quads (nodes), one atomic per col
#pragma unroll
    for (int j = 0; j < 4; j++) {
        float s = cs[j];
        s += __shfl_xor(s, 16); s += __shfl_xor(s, 32);
        if (quad == 0) atomicAdd(&hsum[b * FD + 64 * w + 16 * j + ln], s);
    }
    __syncthreads();
    if (tid < 64 && tid < nvalid)
        scores[off + n0 + tid] = red[0][tid] + red[1][tid] + red[2][tid] + red[3][tid];
}

// ---------------------------------------------------------------------------
// K2+K3 fused, v2: same algebra as round 3, but the walk's hot loops use
// per-lane b128 burst loads + v_readlane (SGPR broadcast) instead of
// wave-uniform LDS reads.  P6 LDS traffic: 5120 -> ~32 reads per CU.
// ---------------------------------------------------------------------------
__global__ __launch_bounds__(1024) void k_graph_walk(
    const float* __restrict__ scores, const float* __restrict__ hsum,
    const float* __restrict__ Wv, const float* __restrict__ bv,
    const float* __restrict__ Wo, const float* __restrict__ bo,
    const float* __restrict__ W2, const float* __restrict__ b2,
    const int* __restrict__ offsets, float* __restrict__ Y)
{
    int b = blockIdx.x, tid = threadIdx.x;
    int off = offsets[b], len = offsets[b + 1] - off;
    int t = tid & 255, g = tid >> 8;
    int lane = tid & 63;

    __shared__ float redm[16], reds[16];
    __shared__ float hs[FD], vs[FD];
    __shared__ float part[4][FD];
    __shared__ float wv2[HID], boS[HID], b2s[OUT_D];
    __shared__ __align__(16) float tOrig[256];
    __shared__ float tS[256], dwS[256], dbS[256];
    __shared__ int   kS[256];
    __shared__ int   cnt[257], startS[257];
    __shared__ float A0s[OUT_D], C0s[OUT_D];
    __shared__ float segA[8][OUT_D], segC[8][OUT_D];
    __shared__ __align__(16) int4 ops4[704];   // packed op records {a,b,n,k}

    // ---- prologue loads (consumed only after barriers below) ----
    if (g == 0) { boS[t] = bo[t]; hs[t] = hsum[b * FD + t]; }
    if (tid < OUT_D) b2s[tid] = b2[tid];
    if (tid <= 256) cnt[tid] = 0;
    float s_n = (tid < len) ? scores[off + tid] : -INFINITY;

    // ---- G1: max over scores ----
    float m = s_n;
#pragma unroll
    for (int d = 1; d < 64; d <<= 1) m = fmaxf(m, __shfl_xor(m, d));
    if ((tid & 63) == 0) redm[tid >> 6] = m;
    __syncthreads();
    m = -INFINITY;
#pragma unroll
    for (int k = 0; k < 16; k++) m = fmaxf(m, redm[k]);

    // ---- G2: exp + sum ----
    float e_n = (tid < len) ? expf(s_n - m) : 0.f;
    float s = e_n;
#pragma unroll
    for (int d = 1; d < 64; d <<= 1) s += __shfl_xor(s, d);
    if ((tid & 63) == 0) reds[tid >> 6] = s;
    __syncthreads();
    s = 0.f;
#pragma unroll
    for (int k = 0; k < 16; k++) s += reds[k];
    float dinv = 1.0f / s;

    // ---- G3: wvec = (hsum @ Wv + len*bv) @ Wo  (4-way split reduction) ----
    float acc = (g == 0) ? (float)len * bv[t] : 0.f;
    for (int f = 64 * g; f < 64 * g + 64; f++) acc = fmaf(hs[f], Wv[f * FD + t], acc);
    part[g][t] = acc;
    __syncthreads();
    if (g == 0) vs[t] = part[0][t] + part[1][t] + part[2][t] + part[3][t];
    __syncthreads();
    float a2 = 0.f;
    for (int f = 64 * g; f < 64 * g + 64; f++) a2 = fmaf(vs[f], Wo[f * HID + t], a2);
    part[g][t] = a2;
    __syncthreads();
    if (g == 0) wv2[t] = part[0][t] + part[1][t] + part[2][t] + part[3][t];
    __syncthreads();   // wv2 ready

    // ---- P0: event construction (active(k,p) := w*p+bo > 0 flips at t=-bo/w) ----
    bool real = false;
    if (tid < 256) {
        float wv = wv2[tid], bvv = boS[tid];
        bool isev = (wv > 0.f && bvv < 0.f) || (wv < 0.f && bvv > 0.f);
        float tk = isev ? (-bvv / wv) : INFINITY;
        real = isev && (tk < INFINITY);
        tOrig[tid] = real ? tk : INFINITY;
    }
    __syncthreads();

    // ---- P1: rank-compare sort (float4 reads: 64 LDS ops/thread, not 256);
    //          A0/C0 partials on all 8 thread-groups in parallel ----
    if (tid < 256) {
        float tk = tOrig[tid];
        int r = 0;
        const float4* t4 = (const float4*)tOrig;
        for (int j4 = 0; j4 < 64; ++j4) {
            float4 tj = t4[j4];
            int e0 = 4 * j4;
            r += (tj.x < tk || (tj.x == tk && (e0 + 0) < tid)) ? 1 : 0;
            r += (tj.y < tk || (tj.y == tk && (e0 + 1) < tid)) ? 1 : 0;
            r += (tj.z < tk || (tj.z == tk && (e0 + 2) < tid)) ? 1 : 0;
            r += (tj.w < tk || (tj.w == tk && (e0 + 3) < tid)) ? 1 : 0;
        }
        tS[r] = tk;
        kS[r] = tid;
        float wv = wv2[tid], bvv = boS[tid];
        dwS[r] = real ? fabsf(wv) : 0.f;   // add-event (w>0): +w ; remove-event (w<0): -w
        dbS[r] = real ? -fabsf(bvv) : 0.f; // add-event: +bo (bo<0) ; remove-event: -bo (bo>0)
    }
    // A0/C0: active set at p->0+ is {k: bo>0 or (bo==0 && w>0)}
    {
        int q = tid >> 7, c = tid & 127;
        float pa = 0.f, pc = 0.f;
        for (int k = q * 32; k < q * 32 + 32; ++k) {
            float v = W2[(size_t)k * OUT_D + c];
            float wv = wv2[k], bvv = boS[k];
            bool ini = (bvv > 0.f) || (bvv == 0.f && wv > 0.f);
            pa = fmaf(ini ? wv : 0.f, v, pa);
            pc = fmaf(ini ? bvv : 0.f, v, pc);
        }
        segA[q][c] = pa; segC[q][c] = pc;
    }
    int nE = __syncthreads_count(real);

    // ---- P2: per-node p + rank (binary search) + histogram; A0/C0 reduce ----
    float p_n = 0.f; int r_n = 0;
    if (tid < len) {
        p_n = e_n * dinv;
        int r = 0;
#pragma unroll
        for (int st = 128; st > 0; st >>= 1)
            if (tS[r + st - 1] < p_n) r += st;
        r_n = r;
        atomicAdd(&cnt[r], 1);
    }
    if (tid < OUT_D) {
        float sa = 0.f, sc2 = 0.f;
#pragma unroll
        for (int q = 0; q < 8; q++) { sa += segA[q][tid]; sc2 += segC[q][tid]; }
        A0s[tid] = sa; C0s[tid] = sc2;
    }
    __syncthreads();

    // ---- P3: exclusive scan of cnt[0..255] by wave 0 (shfl, no barriers) ----
    if (tid < 64) {
        int l = tid;
        int v0 = cnt[4 * l], v1 = cnt[4 * l + 1], v2 = cnt[4 * l + 2], v3 = cnt[4 * l + 3];
        int s0 = v0, s1 = s0 + v1, s2 = s1 + v2, s3 = s2 + v3;
        int run = s3;
#pragma unroll
        for (int d = 1; d < 64; d <<= 1) {
            int t2 = __shfl_up(run, d);
            if (l >= d) run += t2;
        }
        int base = run - s3;   // exclusive over lanes
        startS[4 * l + 0] = base;      cnt[4 * l + 0] = base;
        startS[4 * l + 1] = base + s0; cnt[4 * l + 1] = base + s0;
        startS[4 * l + 2] = base + s1; cnt[4 * l + 2] = base + s1;
        startS[4 * l + 3] = base + s2; cnt[4 * l + 3] = base + s2;
        if (l == 63) { startS[256] = base + s3; cnt[256] = base + s3; }
    }
    __syncthreads();

    int L    = len + nE;
    int Lpad = (L + 7) & ~7;
    int Lseg = ((Lpad + 63) >> 6) << 3;   // ceil(Lpad/8) to mult of 8; 16..80
    int sg = tid >> 7, c = tid & 127;

    // ---- P4: build packed op list {a, b, n, k}; pad [L,704) with no-ops ----
    if (tid < len) {
        int slot = atomicAdd(&cnt[r_n], 1);
        int pos = slot + r_n;
        ops4[pos] = make_int4(__float_as_int(p_n), 0, tid, 0);
    }
    if (tid < nE) {
        int pos = startS[tid + 1] + tid;
        ops4[pos] = make_int4(__float_as_int(dwS[tid]), __float_as_int(dbS[tid]), -1, kS[tid]);
    }
    for (int i = L + tid; i < 704; i += 1024)
        ops4[i] = make_int4(0, 0, -1, 0);   // zero-delta event: harmless no-op
    __syncthreads();

    // ---- burst-load the whole segment into registers: 2 x ds_read_b128 ----
    int i0 = sg * Lseg;
    int4 cur = ops4[i0 + lane];          // ops i0 .. i0+63
    int4 nxt = ops4[i0 + 64 + lane];     // ops i0+64 .. i0+127 (padding beyond)

    // ---- P5: per-segment event-delta sums via readlane (no LDS in loop) ----
    {
        float dA = 0.f, dC = 0.f;
        for (int ii = 0; ii < Lseg; ii += 8) {
            int4 rc = (ii < 64) ? cur : nxt;
            int bb = ii & 63;
#pragma unroll
            for (int d = 0; d < 8; ++d) {
                int nI = __builtin_amdgcn_readlane(rc.z, bb + d);
                if (nI < 0) {
                    float aI = __uint_as_float((unsigned)__builtin_amdgcn_readlane(rc.x, bb + d));
                    float bI = __uint_as_float((unsigned)__builtin_amdgcn_readlane(rc.y, bb + d));
                    int   kI = __builtin_amdgcn_readlane(rc.w, bb + d);
                    float v = W2[(size_t)kI * OUT_D + c];
                    dA = fmaf(aI, v, dA);
                    dC = fmaf(bI, v, dC);
                }
            }
        }
        segA[sg][c] = dA; segC[sg][c] = dC;
    }
    __syncthreads();

    // ---- P6: segment walks via readlane; W2 ring prefetch 8 deep ----
    {
        float A = A0s[c], C = C0s[c];
        for (int s2 = 0; s2 < sg; ++s2) { A += segA[s2][c]; C += segC[s2][c]; }
        float b2v = b2s[c];
        float* Yb = Y + (size_t)off * OUT_D + c;

        float rV[8];
#pragma unroll
        for (int d = 0; d < 8; ++d) {
            int nU = __builtin_amdgcn_readlane(cur.z, d);
            int kU = __builtin_amdgcn_readlane(cur.w, d);
            if (nU < 0) rV[d] = W2[(size_t)kU * OUT_D + c];
            else        rV[d] = 0.f;
        }
        for (int ii = 0; ii < Lseg; ii += 8) {
            int4 rc = (ii < 64) ? cur : nxt;
            int bc = ii & 63;
            int4 rp = (ii + 8 < 64) ? cur : nxt;
            int bp = (ii + 8) & 63;
#pragma unroll
            for (int d = 0; d < 8; ++d) {
                float aI = __uint_as_float((unsigned)__builtin_amdgcn_readlane(rc.x, bc + d));
                int   nI = __builtin_amdgcn_readlane(rc.z, bc + d);
                int   np = __builtin_amdgcn_readlane(rp.z, bp + d);
                int   kp = __builtin_amdgcn_readlane(rp.w, bp + d);
                float vv = rV[d];
                if (nI >= 0) {
                    Yb[(size_t)nI * OUT_D] = fmaf(aI, A, C) + b2v;
                } else {
                    float bI = __uint_as_float((unsigned)__builtin_amdgcn_readlane(rc.y, bc + d));
                    A = fmaf(aI, vv, A);
                    C = fmaf(bI, vv, C);
                }
                if (np < 0) rV[d] = W2[(size_t)kp * OUT_D + c];
            }
        }
    }
}

// ---------------------------------------------------------------------------
extern "C" void kernel_launch(void* const* d_in, const int* in_sizes, int n_in,
                              void* d_out, int out_size, void* d_ws, size_t ws_size,
                              hipStream_t stream)
{
    const float* X        = (const float*)d_in[0];
    const float* text_emb = (const float*)d_in[1];
    const int*   lens     = (const int*)d_in[2];
    const float* W0       = (const float*)d_in[3];
    const float* b0       = (const float*)d_in[4];
    const float* Wq       = (const float*)d_in[5];
    const float* bq       = (const float*)d_in[6];
    const float* Wk       = (const float*)d_in[7];
    // d_in[8] = bk : softmax-invariant, unused
    const float* Wv       = (const float*)d_in[9];
    const float* bv       = (const float*)d_in[10];
    const float* Wo       = (const float*)d_in[11];
    const float* bo       = (const float*)d_in[12];
    const float* W2       = (const float*)d_in[13];
    const float* b2       = (const float*)d_in[14];
    float* Y = (float*)d_out;

    char* base = (char*)d_ws;
    size_t o = 0;
    int*   offsets = (int*)(base + o);            o += 1088;
    float* qkbuf   = (float*)(base + o);          o += 262144;
    float* hsum    = (float*)(base + o);          o += 262144;
    float* scores  = (float*)(base + o);          o += 262144;
    unsigned short* W0sH = (unsigned short*)(base + o); o += 65536;
    unsigned short* W0sL = (unsigned short*)(base + o); o += 65536;

    k_prepA<<<261, 256, 0, stream>>>(text_emb, Wq, bq, Wk, W0, lens,
                                     qkbuf, offsets, hsum, W0sH, W0sL);
    k_l0_mfma<<<dim3(6, B_G), 256, 0, stream>>>(X, W0sH, W0sL, b0, qkbuf, offsets, scores, hsum);
    k_graph_walk<<<B_G, 1024, 0, stream>>>(scores, hsum, Wv, bv, Wo, bo, W2, b2, offsets, Y);
}